// Round 2
// baseline (4062.733 us; speedup 1.0000x reference)
//
#include <hip/hip_runtime.h>
#include <hip/hip_bf16.h>
#include <stdint.h>

#define B_ 256
#define T_ 512
#define C_ 14
#define CO_ 32
#define H_ 128
#define G_ 512   // 4*H

// ---------------- Kernel 1: conv over time + Leaky spike -> 32-bit masks ----
__global__ __launch_bounds__(256) void k_conv_spike(
    const float* __restrict__ x, const float* __restrict__ cw,
    const float* __restrict__ cb, unsigned int* __restrict__ cur1) {
  __shared__ float w_s[CO_ * C_ * 3];  // 1344
  __shared__ float b_s[CO_];
  for (int i = threadIdx.x; i < CO_ * C_ * 3; i += blockDim.x) w_s[i] = cw[i];
  if (threadIdx.x < CO_) b_s[threadIdx.x] = cb[threadIdx.x];
  __syncthreads();
  int idx = blockIdx.x * blockDim.x + threadIdx.x;  // b*T + t
  if (idx >= B_ * T_) return;
  int b = idx / T_, t = idx % T_;
  float xin[3][C_];
#pragma unroll
  for (int k = 0; k < 3; ++k) {
    int tt = t + k - 1;
    if (tt < 0 || tt >= T_) {
#pragma unroll
      for (int c = 0; c < C_; ++c) xin[k][c] = 0.f;
    } else {
      const float* p = x + ((size_t)b * T_ + tt) * C_;
#pragma unroll
      for (int c = 0; c < C_; ++c) xin[k][c] = p[c];
    }
  }
  unsigned int bits = 0u;
  for (int oc = 0; oc < CO_; ++oc) {
    float s = b_s[oc];
    const float* wr = &w_s[oc * C_ * 3];
#pragma unroll
    for (int ic = 0; ic < C_; ++ic)
#pragma unroll
      for (int k = 0; k < 3; ++k) s = fmaf(xin[k][ic], wr[ic * 3 + k], s);
    if (s - 1.0f > 0.f) bits |= (1u << oc);
  }
  cur1[idx] = bits;
}

// ---------------- Kernel 2: SLSTM layer 1 (2 rows/block, half-gate/thread) --
// thread i: gate g = i>>1, half hf = i&1. Each thread holds 64 w_hh weights
// and 16 w_ih weights in REGISTERS; partner lanes (i, i^1) combine partial
// dots with one __shfl_xor. 1024 thr/block, 256 blocks, 4 waves/SIMD.
__global__ __launch_bounds__(1024, 4) void k_slstm1(
    const unsigned int* __restrict__ cur1, const float* __restrict__ w_ih,
    const float* __restrict__ w_hh, const float* __restrict__ b_ih,
    const float* __restrict__ b_hh, const float* __restrict__ thr_p,
    unsigned long long* __restrict__ spk_bits, unsigned int* __restrict__ count) {
  const int i = threadIdx.x;
  const int g = i >> 1;
  const int hf = i & 1;
  const int t0 = blockIdx.x * 2;
  const float thr = thr_p[0];

  float whh[64];
#pragma unroll
  for (int k = 0; k < 64; ++k) whh[k] = w_hh[g * H_ + hf * 64 + k];
  float wih[16];
#pragma unroll
  for (int k = 0; k < 16; ++k) wih[k] = w_ih[g * 32 + hf * 16 + k];
  const float bias = hf ? 0.f : (b_ih[g] + b_hh[g]);

  __shared__ float mem_s[2][H_];
  __shared__ float gate_s[2][G_];
  float syn = 0.f;  // live only in update threads (i<256)
  int cnt = 0;
  if (i < 256) mem_s[i >> 7][i & 127] = 0.f;
  __syncthreads();

  for (int b = 0; b < B_; ++b) {
    // uniform loads; issued early, consumed after the FMA loops
    const unsigned int bits0 = cur1[b * T_ + t0];
    const unsigned int bits1 = cur1[b * T_ + t0 + 1];

    const float* m0 = &mem_s[0][hf * 64];
    const float* m1 = &mem_s[1][hf * 64];
    float a0 = bias, a1 = 0.f, a2 = 0.f, a3 = 0.f;
    float c0 = bias, c1 = 0.f, c2 = 0.f, c3 = 0.f;
#pragma unroll
    for (int k = 0; k < 16; ++k) {
      a0 = fmaf(whh[k], m0[k], a0);
      a1 = fmaf(whh[k + 16], m0[k + 16], a1);
      a2 = fmaf(whh[k + 32], m0[k + 32], a2);
      a3 = fmaf(whh[k + 48], m0[k + 48], a3);
      c0 = fmaf(whh[k], m1[k], c0);
      c1 = fmaf(whh[k + 16], m1[k + 16], c1);
      c2 = fmaf(whh[k + 32], m1[k + 32], c2);
      c3 = fmaf(whh[k + 48], m1[k + 48], c3);
    }
    const unsigned int ub0 = bits0 >> (hf * 16);
    const unsigned int ub1 = bits1 >> (hf * 16);
#pragma unroll
    for (int k = 0; k < 16; ++k) {
      a0 += ((ub0 >> k) & 1u) ? wih[k] : 0.f;
      c0 += ((ub1 >> k) & 1u) ? wih[k] : 0.f;
    }
    float s0 = (a0 + a1) + (a2 + a3);
    float s1 = (c0 + c1) + (c2 + c3);
    s0 += __shfl_xor(s0, 1);
    s1 += __shfl_xor(s1, 1);
    if (!hf) {
      gate_s[0][g] = s0;
      gate_s[1][g] = s1;
    }
    __syncthreads();
    if (i < 256) {
      const int r = i >> 7, h = i & 127;
      float gi = gate_s[r][h];
      float gf = gate_s[r][h + 128];
      float gg = gate_s[r][h + 256];
      float go = gate_s[r][h + 384];
      float ii = 1.f / (1.f + expf(-gi));
      float ff = 1.f / (1.f + expf(-gf));
      float gt = tanhf(gg);
      float oo = 1.f / (1.f + expf(-go));
      float memp = mem_s[r][h];
      float rst = (memp - thr > 0.f) ? thr : 0.f;  // reset * thr (detached)
      syn = ff * syn + ii * gt;
      float mm = oo * tanhf(syn) - rst;
      mem_s[r][h] = mm;
      bool spk = (mm - thr) > 0.f;
      cnt += spk ? 1 : 0;
      unsigned long long m = __ballot(spk);
      if ((i & 63) == 0)
        spk_bits[((size_t)b * T_ + t0 + r) * 2 + ((h >> 6) & 1)] = m;
    }
    __syncthreads();
  }
  if (i < 256) atomicAdd(&count[i & 127], (unsigned int)cnt);
}

// ---------------- Kernel 3: BN params from spike counts --------------------
__global__ void k_bnprep(const unsigned int* __restrict__ count,
                         const float* __restrict__ gamma,
                         const float* __restrict__ beta,
                         float* __restrict__ a, float* __restrict__ c) {
  int h = threadIdx.x;
  if (h >= H_) return;
  const float inv_n = 1.f / (float)(B_ * T_);
  float mu = (float)count[h] * inv_n;
  float var = mu * (1.f - mu);
  float ai = gamma[h] / sqrtf(var + 1e-5f);
  a[h] = ai;
  c[h] = beta[h] - mu * ai;
}

// ---------------- Kernel 4: fold BN into layer-2 input weights -------------
__global__ void k_fold(const float* __restrict__ w_ih2,
                       const float* __restrict__ b_ih2,
                       const float* __restrict__ b_hh2,
                       const float* __restrict__ a, const float* __restrict__ c,
                       float* __restrict__ W2p, float* __restrict__ cg) {
  int gi = blockIdx.x * blockDim.x + threadIdx.x;  // 0..511
  if (gi >= G_) return;
  float s = b_ih2[gi] + b_hh2[gi];
  for (int h = 0; h < H_; ++h) {
    float w = w_ih2[gi * H_ + h];
    W2p[h * G_ + gi] = w * a[h];  // [h][512]
    s = fmaf(w, c[h], s);
  }
  cg[gi] = s;
}

// ---------------- Kernel 5: SLSTM layer 2 (+ mean-over-b accum) ------------
__global__ __launch_bounds__(1024, 4) void k_slstm2(
    const unsigned long long* __restrict__ spk_bits,
    const float* __restrict__ w_hh, const float* __restrict__ W2p,
    const float* __restrict__ cg, const float* __restrict__ thr_p,
    float* __restrict__ acc_out) {
  const int i = threadIdx.x;
  const int g = i >> 1;
  const int hf = i & 1;
  const int t0 = blockIdx.x * 2;
  const float thr = thr_p[0];

  float whh[64];
#pragma unroll
  for (int k = 0; k < 64; ++k) whh[k] = w_hh[g * H_ + hf * 64 + k];
  const float bias = hf ? 0.f : cg[g];

  __shared__ float mem_s[2][H_];
  __shared__ float gate_s[2][G_];
  float syn = 0.f, accv = 0.f;
  if (i < 256) mem_s[i >> 7][i & 127] = 0.f;
  __syncthreads();

  for (int b = 0; b < B_; ++b) {
    unsigned long long m0b = spk_bits[((size_t)b * T_ + t0) * 2 + hf];
    unsigned long long m1b = spk_bits[((size_t)b * T_ + t0 + 1) * 2 + hf];

    const float* m0 = &mem_s[0][hf * 64];
    const float* m1 = &mem_s[1][hf * 64];
    float a0 = bias, a1 = 0.f, a2 = 0.f, a3 = 0.f;
    float c0 = bias, c1 = 0.f, c2 = 0.f, c3 = 0.f;
#pragma unroll
    for (int k = 0; k < 16; ++k) {
      a0 = fmaf(whh[k], m0[k], a0);
      a1 = fmaf(whh[k + 16], m0[k + 16], a1);
      a2 = fmaf(whh[k + 32], m0[k + 32], a2);
      a3 = fmaf(whh[k + 48], m0[k + 48], a3);
      c0 = fmaf(whh[k], m1[k], c0);
      c1 = fmaf(whh[k + 16], m1[k + 16], c1);
      c2 = fmaf(whh[k + 32], m1[k + 32], c2);
      c3 = fmaf(whh[k + 48], m1[k + 48], c3);
    }
    // sparse input term (layer-1 spikes; typically empty)
    while (m0b) {
      int h = __ffsll(m0b) - 1; m0b &= m0b - 1;
      a0 += W2p[(size_t)(hf * 64 + h) * G_ + g];
    }
    while (m1b) {
      int h = __ffsll(m1b) - 1; m1b &= m1b - 1;
      c0 += W2p[(size_t)(hf * 64 + h) * G_ + g];
    }
    float s0 = (a0 + a1) + (a2 + a3);
    float s1 = (c0 + c1) + (c2 + c3);
    s0 += __shfl_xor(s0, 1);
    s1 += __shfl_xor(s1, 1);
    if (!hf) {
      gate_s[0][g] = s0;
      gate_s[1][g] = s1;
    }
    __syncthreads();
    if (i < 256) {
      const int r = i >> 7, h = i & 127;
      float gi = gate_s[r][h];
      float gf = gate_s[r][h + 128];
      float gg = gate_s[r][h + 256];
      float go = gate_s[r][h + 384];
      float ii = 1.f / (1.f + expf(-gi));
      float ff = 1.f / (1.f + expf(-gf));
      float gt = tanhf(gg);
      float oo = 1.f / (1.f + expf(-go));
      float memp = mem_s[r][h];
      float rst = (memp - thr > 0.f) ? thr : 0.f;
      syn = ff * syn + ii * gt;
      float mm = oo * tanhf(syn) - rst;
      mem_s[r][h] = mm;
      accv += mm;
    }
    __syncthreads();
  }
  if (i < 256) acc_out[(size_t)(t0 + (i >> 7)) * H_ + (i & 127)] = accv;
}

// ---------------- Kernel 6: final mean + FC --------------------------------
__global__ void k_out(const float* __restrict__ accv,
                      const float* __restrict__ fc_w,
                      const float* __restrict__ fc_b, float* __restrict__ out) {
  int idx = blockIdx.x * blockDim.x + threadIdx.x;  // t*8+n
  if (idx >= T_ * 8) return;
  int t = idx >> 3, n = idx & 7;
  float s = fc_b[n];
  for (int h = 0; h < H_; ++h)
    s = fmaf(accv[t * H_ + h] * (1.f / 256.f), fc_w[n * H_ + h], s);
  out[idx] = s;
}

extern "C" void kernel_launch(void* const* d_in, const int* in_sizes, int n_in,
                              void* d_out, int out_size, void* d_ws, size_t ws_size,
                              hipStream_t stream) {
  const float* x       = (const float*)d_in[0];
  const float* conv_w  = (const float*)d_in[1];
  const float* conv_b  = (const float*)d_in[2];
  const float* w_ih1   = (const float*)d_in[3];
  const float* w_hh1   = (const float*)d_in[4];
  const float* b_ih1   = (const float*)d_in[5];
  const float* b_hh1   = (const float*)d_in[6];
  const float* thr1    = (const float*)d_in[7];
  const float* w_ih2   = (const float*)d_in[8];
  const float* w_hh2   = (const float*)d_in[9];
  const float* b_ih2   = (const float*)d_in[10];
  const float* b_hh2   = (const float*)d_in[11];
  const float* thr2    = (const float*)d_in[12];
  const float* bn_g    = (const float*)d_in[13];
  const float* bn_b    = (const float*)d_in[14];
  const float* fc_w    = (const float*)d_in[15];
  const float* fc_b    = (const float*)d_in[16];
  float* out = (float*)d_out;

  char* ws = (char*)d_ws;
  unsigned int* cur1       = (unsigned int*)(ws);                    // 512 KB
  unsigned long long* spk  = (unsigned long long*)(ws + (512 << 10));// 2 MB
  unsigned int* count      = (unsigned int*)(ws + (2560 << 10));     // 512 B
  float* a                 = (float*)(ws + (2561 << 10));            // 512 B
  float* c                 = (float*)(ws + (2562 << 10));            // 512 B
  float* cg                = (float*)(ws + (2563 << 10));            // 2 KB
  float* W2p               = (float*)(ws + (2566 << 10));            // 256 KB
  float* accv              = (float*)(ws + (2822 << 10));            // 256 KB

  hipMemsetAsync(count, 0, H_ * sizeof(unsigned int), stream);
  k_conv_spike<<<(B_ * T_ + 255) / 256, 256, 0, stream>>>(x, conv_w, conv_b, cur1);
  k_slstm1<<<T_ / 2, 1024, 0, stream>>>(cur1, w_ih1, w_hh1, b_ih1, b_hh1, thr1,
                                        spk, count);
  k_bnprep<<<1, 128, 0, stream>>>(count, bn_g, bn_b, a, c);
  k_fold<<<1, 512, 0, stream>>>(w_ih2, b_ih2, b_hh2, a, c, W2p, cg);
  k_slstm2<<<T_ / 2, 1024, 0, stream>>>(spk, w_hh2, W2p, cg, thr2, accv);
  k_out<<<(T_ * 8 + 255) / 256, 256, 0, stream>>>(accv, fc_w, fc_b, out);
}

// Round 3
// 419.370 us; speedup vs baseline: 9.6877x; 9.6877x over previous
//
#include <hip/hip_runtime.h>
#include <hip/hip_bf16.h>
#include <stdint.h>

#define B_ 256
#define T_ 512
#define C_ 14
#define CO_ 32
#define H_ 128
#define G_ 512   // 4*H

typedef float f32x16 __attribute__((ext_vector_type(16)));

// ---------------- Kernel 0: fast-path flag ---------------------------------
// mem = o*tanh(syn) - reset*thr is strictly < 1 (sigmoid<1, |tanh|<1).
// Spike needs mem - thr > 0, impossible when thr >= 1 -> layer-1 spikes are
// identically zero for ANY inputs when thr1 >= 1. Guard at runtime.
__global__ void k_flag(const float* __restrict__ thr1, int* __restrict__ flag) {
  if (threadIdx.x == 0) flag[0] = (thr1[0] >= 1.0f) ? 1 : 0;
}

// ---------------- Kernel 1: conv over time + Leaky spike -> 32-bit masks ----
__global__ __launch_bounds__(256) void k_conv_spike(
    const int* __restrict__ flag, const float* __restrict__ x,
    const float* __restrict__ cw, const float* __restrict__ cb,
    unsigned int* __restrict__ cur1) {
  if (flag[0]) return;  // fast path: cur1 never read
  __shared__ float w_s[CO_ * C_ * 3];
  __shared__ float b_s[CO_];
  for (int i = threadIdx.x; i < CO_ * C_ * 3; i += blockDim.x) w_s[i] = cw[i];
  if (threadIdx.x < CO_) b_s[threadIdx.x] = cb[threadIdx.x];
  __syncthreads();
  int idx = blockIdx.x * blockDim.x + threadIdx.x;  // b*T + t
  if (idx >= B_ * T_) return;
  int b = idx / T_, t = idx % T_;
  float xin[3][C_];
#pragma unroll
  for (int k = 0; k < 3; ++k) {
    int tt = t + k - 1;
    if (tt < 0 || tt >= T_) {
#pragma unroll
      for (int c = 0; c < C_; ++c) xin[k][c] = 0.f;
    } else {
      const float* p = x + ((size_t)b * T_ + tt) * C_;
#pragma unroll
      for (int c = 0; c < C_; ++c) xin[k][c] = p[c];
    }
  }
  unsigned int bits = 0u;
  for (int oc = 0; oc < CO_; ++oc) {
    float s = b_s[oc];
    const float* wr = &w_s[oc * C_ * 3];
#pragma unroll
    for (int ic = 0; ic < C_; ++ic)
#pragma unroll
      for (int k = 0; k < 3; ++k) s = fmaf(xin[k][ic], wr[ic * 3 + k], s);
    if (s - 1.0f > 0.f) bits |= (1u << oc);
  }
  cur1[idx] = bits;
}

// ---------------- Kernel 2: honest SLSTM layer 1 (fallback only) -----------
__global__ __launch_bounds__(512, 2) void k_slstm1(
    const int* __restrict__ flag, const unsigned int* __restrict__ cur1,
    const float* __restrict__ w_ih, const float* __restrict__ w_hh,
    const float* __restrict__ b_ih, const float* __restrict__ b_hh,
    const float* __restrict__ thr_p, unsigned long long* __restrict__ spk_bits,
    unsigned int* __restrict__ count) {
  if (flag[0]) return;  // fast path: spikes provably zero; count stays 0
  const int g = threadIdx.x;
  const int t0 = blockIdx.x * 2;
  const float thr = thr_p[0];
  float wih[32], whh[H_];
#pragma unroll
  for (int k = 0; k < 32; ++k) wih[k] = w_ih[g * 32 + k];
#pragma unroll
  for (int k = 0; k < H_; ++k) whh[k] = w_hh[g * H_ + k];
  const float bias = b_ih[g] + b_hh[g];
  __shared__ float mem_s[2][H_];
  __shared__ float gate_s[2][G_];
  float syn = 0.f;
  int cnt = 0;
  if (g < 256) mem_s[g >> 7][g & 127] = 0.f;
  __syncthreads();
  for (int b = 0; b < B_; ++b) {
    unsigned int bits0 = cur1[b * T_ + t0];
    unsigned int bits1 = cur1[b * T_ + t0 + 1];
    float s0 = bias, s1 = bias;
#pragma unroll
    for (int k = 0; k < 32; ++k) {
      s0 += ((bits0 >> k) & 1u) ? wih[k] : 0.f;
      s1 += ((bits1 >> k) & 1u) ? wih[k] : 0.f;
    }
#pragma unroll
    for (int k = 0; k < H_; ++k) {
      s0 = fmaf(whh[k], mem_s[0][k], s0);
      s1 = fmaf(whh[k], mem_s[1][k], s1);
    }
    gate_s[0][g] = s0;
    gate_s[1][g] = s1;
    __syncthreads();
    if (g < 256) {
      const int r = g >> 7, h = g & 127;
      float gi = gate_s[r][h];
      float gf = gate_s[r][h + 128];
      float gg = gate_s[r][h + 256];
      float go = gate_s[r][h + 384];
      float ii = 1.f / (1.f + expf(-gi));
      float ff = 1.f / (1.f + expf(-gf));
      float gt = tanhf(gg);
      float oo = 1.f / (1.f + expf(-go));
      float memp = mem_s[r][h];
      float rst = (memp - thr > 0.f) ? thr : 0.f;
      syn = ff * syn + ii * gt;
      float mm = oo * tanhf(syn) - rst;
      mem_s[r][h] = mm;
      bool spk = (mm - thr) > 0.f;
      cnt += spk ? 1 : 0;
      unsigned long long m = __ballot(spk);
      if ((g & 63) == 0)
        spk_bits[((size_t)b * T_ + t0 + r) * 2 + ((h >> 6) & 1)] = m;
    }
    __syncthreads();
  }
  if (g < 256) atomicAdd(&count[g & 127], (unsigned int)cnt);
}

// ---------------- Kernel 3: BN params from spike counts --------------------
__global__ void k_bnprep(const unsigned int* __restrict__ count,
                         const float* __restrict__ gamma,
                         const float* __restrict__ beta,
                         float* __restrict__ a, float* __restrict__ c) {
  int h = threadIdx.x;
  if (h >= H_) return;
  const float inv_n = 1.f / (float)(B_ * T_);
  float mu = (float)count[h] * inv_n;
  float var = mu * (1.f - mu);
  float ai = gamma[h] / sqrtf(var + 1e-5f);
  a[h] = ai;
  c[h] = beta[h] - mu * ai;
}

// ---------------- Kernel 4: fold BN into layer-2 input weights -------------
__global__ void k_fold(const float* __restrict__ w_ih2,
                       const float* __restrict__ b_ih2,
                       const float* __restrict__ b_hh2,
                       const float* __restrict__ a, const float* __restrict__ c,
                       float* __restrict__ W2p, float* __restrict__ cg) {
  int gi = blockIdx.x * blockDim.x + threadIdx.x;  // 0..511
  if (gi >= G_) return;
  float s = b_ih2[gi] + b_hh2[gi];
  for (int h = 0; h < H_; ++h) {
    float w = w_ih2[gi * H_ + h];
    W2p[h * G_ + gi] = w * a[h];
    s = fmaf(w, c[h], s);
  }
  cg[gi] = s;
}

// ---------------- Kernel 5: honest SLSTM layer 2 (fallback only) -----------
__global__ __launch_bounds__(512, 2) void k_slstm2(
    const int* __restrict__ flag, const unsigned long long* __restrict__ spk_bits,
    const float* __restrict__ w_hh, const float* __restrict__ W2p,
    const float* __restrict__ cg, const float* __restrict__ thr_p,
    float* __restrict__ acc_out) {
  if (flag[0]) return;  // fast path handled by k_traj
  const int g = threadIdx.x;
  const int t0 = blockIdx.x * 2;
  const float thr = thr_p[0];
  float whh[H_];
#pragma unroll
  for (int k = 0; k < H_; ++k) whh[k] = w_hh[g * H_ + k];
  const float bias = cg[g];
  __shared__ float mem_s[2][H_];
  __shared__ float gate_s[2][G_];
  float syn = 0.f, accv = 0.f;
  if (g < 256) mem_s[g >> 7][g & 127] = 0.f;
  __syncthreads();
  for (int b = 0; b < B_; ++b) {
    unsigned long long m00 = spk_bits[((size_t)b * T_ + t0) * 2 + 0];
    unsigned long long m01 = spk_bits[((size_t)b * T_ + t0) * 2 + 1];
    unsigned long long m10 = spk_bits[((size_t)b * T_ + t0 + 1) * 2 + 0];
    unsigned long long m11 = spk_bits[((size_t)b * T_ + t0 + 1) * 2 + 1];
    float s0 = bias, s1 = bias;
    while (m00) { int h = __ffsll(m00) - 1; m00 &= m00 - 1; s0 += W2p[h * G_ + g]; }
    while (m01) { int h = __ffsll(m01) - 1; m01 &= m01 - 1; s0 += W2p[(h + 64) * G_ + g]; }
    while (m10) { int h = __ffsll(m10) - 1; m10 &= m10 - 1; s1 += W2p[h * G_ + g]; }
    while (m11) { int h = __ffsll(m11) - 1; m11 &= m11 - 1; s1 += W2p[(h + 64) * G_ + g]; }
#pragma unroll
    for (int k = 0; k < H_; ++k) {
      s0 = fmaf(whh[k], mem_s[0][k], s0);
      s1 = fmaf(whh[k], mem_s[1][k], s1);
    }
    gate_s[0][g] = s0;
    gate_s[1][g] = s1;
    __syncthreads();
    if (g < 256) {
      const int r = g >> 7, h = g & 127;
      float gi = gate_s[r][h];
      float gf = gate_s[r][h + 128];
      float gg = gate_s[r][h + 256];
      float go = gate_s[r][h + 384];
      float ii = 1.f / (1.f + expf(-gi));
      float ff = 1.f / (1.f + expf(-gf));
      float gt = tanhf(gg);
      float oo = 1.f / (1.f + expf(-go));
      float memp = mem_s[r][h];
      float rst = (memp - thr > 0.f) ? thr : 0.f;
      syn = ff * syn + ii * gt;
      float mm = oo * tanhf(syn) - rst;
      mem_s[r][h] = mm;
      accv += mm;
    }
    __syncthreads();
  }
  if (g < 256) acc_out[(size_t)(t0 + (g >> 7)) * H_ + (g & 127)] = accv;
}

// ---------------- Kernel 5b: FAST layer 2 — single shared trajectory -------
// When thr1>=1: layer-2 input = beta (constant over rows & steps), so every
// row t has the identical trajectory. Run it once, FC, broadcast.
// Weights live in 8 named f32x16 SSA values -> guaranteed VGPRs (no arrays).
#define ACC16(W, OFF)                                                    \
  {                                                                      \
    float4 m0_ = *(const float4*)&mem_s[(OFF)];                          \
    float4 m1_ = *(const float4*)&mem_s[(OFF) + 4];                      \
    float4 m2_ = *(const float4*)&mem_s[(OFF) + 8];                      \
    float4 m3_ = *(const float4*)&mem_s[(OFF) + 12];                     \
    a0 = fmaf(W[0], m0_.x, a0); a1 = fmaf(W[1], m0_.y, a1);              \
    a2 = fmaf(W[2], m0_.z, a2); a3 = fmaf(W[3], m0_.w, a3);              \
    a0 = fmaf(W[4], m1_.x, a0); a1 = fmaf(W[5], m1_.y, a1);              \
    a2 = fmaf(W[6], m1_.z, a2); a3 = fmaf(W[7], m1_.w, a3);              \
    a0 = fmaf(W[8], m2_.x, a0); a1 = fmaf(W[9], m2_.y, a1);              \
    a2 = fmaf(W[10], m2_.z, a2); a3 = fmaf(W[11], m2_.w, a3);            \
    a0 = fmaf(W[12], m3_.x, a0); a1 = fmaf(W[13], m3_.y, a1);            \
    a2 = fmaf(W[14], m3_.z, a2); a3 = fmaf(W[15], m3_.w, a3);            \
  }

__global__ __launch_bounds__(512, 2) void k_traj(
    const int* __restrict__ flag, const float* __restrict__ w_hh,
    const float* __restrict__ cg, const float* __restrict__ thr_p,
    const float* __restrict__ fc_w, const float* __restrict__ fc_b,
    float* __restrict__ out) {
  if (!flag[0]) return;
  const int g = threadIdx.x;
  const float thr = thr_p[0];
  const float* wr = w_hh + (size_t)g * H_;
  f32x16 w0 = *(const f32x16*)(wr);
  f32x16 w1 = *(const f32x16*)(wr + 16);
  f32x16 w2 = *(const f32x16*)(wr + 32);
  f32x16 w3 = *(const f32x16*)(wr + 48);
  f32x16 w4 = *(const f32x16*)(wr + 64);
  f32x16 w5 = *(const f32x16*)(wr + 80);
  f32x16 w6 = *(const f32x16*)(wr + 96);
  f32x16 w7 = *(const f32x16*)(wr + 112);
  const float bias = cg[g];

  __shared__ float mem_s[H_];
  __shared__ float gate_s[G_];
  __shared__ float red_s[H_ + 8];
  float syn = 0.f, accm = 0.f;
  if (g < H_) mem_s[g] = 0.f;
  __syncthreads();

  for (int b = 0; b < B_; ++b) {
    float a0 = bias, a1 = 0.f, a2 = 0.f, a3 = 0.f;
    ACC16(w0, 0)  ACC16(w1, 16) ACC16(w2, 32) ACC16(w3, 48)
    ACC16(w4, 64) ACC16(w5, 80) ACC16(w6, 96) ACC16(w7, 112)
    gate_s[g] = (a0 + a1) + (a2 + a3);
    __syncthreads();
    if (g < H_) {
      float gi = gate_s[g];
      float gf = gate_s[g + 128];
      float gg = gate_s[g + 256];
      float go = gate_s[g + 384];
      float ii = 1.f / (1.f + expf(-gi));
      float ff = 1.f / (1.f + expf(-gf));
      float gt = tanhf(gg);
      float oo = 1.f / (1.f + expf(-go));
      float memp = mem_s[g];
      float rst = (memp - thr > 0.f) ? thr : 0.f;  // honest (thr2 may be <1)
      syn = ff * syn + ii * gt;
      float mm = oo * tanhf(syn) - rst;
      mem_s[g] = mm;
      accm += mm;
    }
    __syncthreads();
  }
  // mean over steps, then FC (8 outputs), then broadcast to all 512 rows
  if (g < H_) red_s[g] = accm * (1.f / 256.f);
  __syncthreads();
  if (g < 8) {
    float s = fc_b[g];
    const float* fw = fc_w + g * H_;
    for (int h = 0; h < H_; ++h) s = fmaf(red_s[h], fw[h], s);
    red_s[H_ + g] = s;
  }
  __syncthreads();
  for (int idx = g; idx < T_ * 8; idx += 512) out[idx] = red_s[H_ + (idx & 7)];
}

// ---------------- Kernel 6: final mean + FC (fallback only) ----------------
__global__ void k_out(const int* __restrict__ flag, const float* __restrict__ accv,
                      const float* __restrict__ fc_w,
                      const float* __restrict__ fc_b, float* __restrict__ out) {
  if (flag[0]) return;
  int idx = blockIdx.x * blockDim.x + threadIdx.x;  // t*8+n
  if (idx >= T_ * 8) return;
  int t = idx >> 3, n = idx & 7;
  float s = fc_b[n];
  for (int h = 0; h < H_; ++h)
    s = fmaf(accv[t * H_ + h] * (1.f / 256.f), fc_w[n * H_ + h], s);
  out[idx] = s;
}

extern "C" void kernel_launch(void* const* d_in, const int* in_sizes, int n_in,
                              void* d_out, int out_size, void* d_ws, size_t ws_size,
                              hipStream_t stream) {
  const float* x       = (const float*)d_in[0];
  const float* conv_w  = (const float*)d_in[1];
  const float* conv_b  = (const float*)d_in[2];
  const float* w_ih1   = (const float*)d_in[3];
  const float* w_hh1   = (const float*)d_in[4];
  const float* b_ih1   = (const float*)d_in[5];
  const float* b_hh1   = (const float*)d_in[6];
  const float* thr1    = (const float*)d_in[7];
  const float* w_ih2   = (const float*)d_in[8];
  const float* w_hh2   = (const float*)d_in[9];
  const float* b_ih2   = (const float*)d_in[10];
  const float* b_hh2   = (const float*)d_in[11];
  const float* thr2    = (const float*)d_in[12];
  const float* bn_g    = (const float*)d_in[13];
  const float* bn_b    = (const float*)d_in[14];
  const float* fc_w    = (const float*)d_in[15];
  const float* fc_b    = (const float*)d_in[16];
  float* out = (float*)d_out;

  char* ws = (char*)d_ws;
  unsigned int* cur1       = (unsigned int*)(ws);                    // 512 KB
  unsigned long long* spk  = (unsigned long long*)(ws + (512 << 10));// 2 MB
  unsigned int* count      = (unsigned int*)(ws + (2560 << 10));     // 512 B
  float* a                 = (float*)(ws + (2561 << 10));            // 512 B
  float* c                 = (float*)(ws + (2562 << 10));            // 512 B
  float* cg                = (float*)(ws + (2563 << 10));            // 2 KB
  float* W2p               = (float*)(ws + (2566 << 10));            // 256 KB
  float* accv              = (float*)(ws + (2822 << 10));            // 256 KB
  int* flag                = (int*)(ws + (3078 << 10));              // 4 B

  hipMemsetAsync(count, 0, H_ * sizeof(unsigned int), stream);
  k_flag<<<1, 64, 0, stream>>>(thr1, flag);
  k_conv_spike<<<(B_ * T_ + 255) / 256, 256, 0, stream>>>(flag, x, conv_w, conv_b, cur1);
  k_slstm1<<<T_ / 2, 512, 0, stream>>>(flag, cur1, w_ih1, w_hh1, b_ih1, b_hh1,
                                       thr1, spk, count);
  k_bnprep<<<1, 128, 0, stream>>>(count, bn_g, bn_b, a, c);
  k_fold<<<1, 512, 0, stream>>>(w_ih2, b_ih2, b_hh2, a, c, W2p, cg);
  k_slstm2<<<T_ / 2, 512, 0, stream>>>(flag, spk, w_hh2, W2p, cg, thr2, accv);
  k_traj<<<1, 512, 0, stream>>>(flag, w_hh2, cg, thr2, fc_w, fc_b, out);
  k_out<<<(T_ * 8 + 255) / 256, 256, 0, stream>>>(flag, accv, fc_w, fc_b, out);
}

// Round 4
// 394.863 us; speedup vs baseline: 10.2890x; 1.0621x over previous
//
#include <hip/hip_runtime.h>
#include <hip/hip_bf16.h>
#include <stdint.h>

#define B_ 256
#define T_ 512
#define C_ 14
#define CO_ 32
#define H_ 128
#define G_ 512   // 4*H

typedef float f32x16 __attribute__((ext_vector_type(16)));

__device__ __forceinline__ float sigm_fast(float x) {
  float e = __expf(-x);
  return __builtin_amdgcn_rcpf(1.f + e);
}
__device__ __forceinline__ float tanh_fast(float x) {
  float e = __expf(2.f * x);               // inf-safe: x>>0 -> 1, x<<0 -> -1
  return 1.f - 2.f * __builtin_amdgcn_rcpf(1.f + e);
}

// ---------------- Kernel 0: fast-path flag ---------------------------------
// mem = o*tanh(syn) - reset*thr is strictly < 1 (sigmoid<1, |tanh|<1).
// Spike needs mem - thr > 0, impossible when thr >= 1 -> layer-1 spikes are
// identically zero for ANY inputs when thr1 >= 1. Guard at runtime.
__global__ void k_flag(const float* __restrict__ thr1, int* __restrict__ flag) {
  if (threadIdx.x == 0) flag[0] = (thr1[0] >= 1.0f) ? 1 : 0;
}

// ---------------- Kernel 1: conv over time + Leaky spike (fallback) --------
__global__ __launch_bounds__(256) void k_conv_spike(
    const int* __restrict__ flag, const float* __restrict__ x,
    const float* __restrict__ cw, const float* __restrict__ cb,
    unsigned int* __restrict__ cur1) {
  if (flag[0]) return;
  __shared__ float w_s[CO_ * C_ * 3];
  __shared__ float b_s[CO_];
  for (int i = threadIdx.x; i < CO_ * C_ * 3; i += blockDim.x) w_s[i] = cw[i];
  if (threadIdx.x < CO_) b_s[threadIdx.x] = cb[threadIdx.x];
  __syncthreads();
  int idx = blockIdx.x * blockDim.x + threadIdx.x;  // b*T + t
  if (idx >= B_ * T_) return;
  int b = idx / T_, t = idx % T_;
  float xin[3][C_];
#pragma unroll
  for (int k = 0; k < 3; ++k) {
    int tt = t + k - 1;
    if (tt < 0 || tt >= T_) {
#pragma unroll
      for (int c = 0; c < C_; ++c) xin[k][c] = 0.f;
    } else {
      const float* p = x + ((size_t)b * T_ + tt) * C_;
#pragma unroll
      for (int c = 0; c < C_; ++c) xin[k][c] = p[c];
    }
  }
  unsigned int bits = 0u;
  for (int oc = 0; oc < CO_; ++oc) {
    float s = b_s[oc];
    const float* wr = &w_s[oc * C_ * 3];
#pragma unroll
    for (int ic = 0; ic < C_; ++ic)
#pragma unroll
      for (int k = 0; k < 3; ++k) s = fmaf(xin[k][ic], wr[ic * 3 + k], s);
    if (s - 1.0f > 0.f) bits |= (1u << oc);
  }
  cur1[idx] = bits;
}

// ---------------- Kernel 2: honest SLSTM layer 1 (fallback only) -----------
__global__ __launch_bounds__(512, 2) void k_slstm1(
    const int* __restrict__ flag, const unsigned int* __restrict__ cur1,
    const float* __restrict__ w_ih, const float* __restrict__ w_hh,
    const float* __restrict__ b_ih, const float* __restrict__ b_hh,
    const float* __restrict__ thr_p, unsigned long long* __restrict__ spk_bits,
    unsigned int* __restrict__ count) {
  if (flag[0]) return;  // fast path: spikes provably zero; count stays 0
  const int g = threadIdx.x;
  const int t0 = blockIdx.x * 2;
  const float thr = thr_p[0];
  float wih[32], whh[H_];
#pragma unroll
  for (int k = 0; k < 32; ++k) wih[k] = w_ih[g * 32 + k];
#pragma unroll
  for (int k = 0; k < H_; ++k) whh[k] = w_hh[g * H_ + k];
  const float bias = b_ih[g] + b_hh[g];
  __shared__ float mem_s[2][H_];
  __shared__ float gate_s[2][G_];
  float syn = 0.f;
  int cnt = 0;
  if (g < 256) mem_s[g >> 7][g & 127] = 0.f;
  __syncthreads();
  for (int b = 0; b < B_; ++b) {
    unsigned int bits0 = cur1[b * T_ + t0];
    unsigned int bits1 = cur1[b * T_ + t0 + 1];
    float s0 = bias, s1 = bias;
#pragma unroll
    for (int k = 0; k < 32; ++k) {
      s0 += ((bits0 >> k) & 1u) ? wih[k] : 0.f;
      s1 += ((bits1 >> k) & 1u) ? wih[k] : 0.f;
    }
#pragma unroll
    for (int k = 0; k < H_; ++k) {
      s0 = fmaf(whh[k], mem_s[0][k], s0);
      s1 = fmaf(whh[k], mem_s[1][k], s1);
    }
    gate_s[0][g] = s0;
    gate_s[1][g] = s1;
    __syncthreads();
    if (g < 256) {
      const int r = g >> 7, h = g & 127;
      float gi = gate_s[r][h];
      float gf = gate_s[r][h + 128];
      float gg = gate_s[r][h + 256];
      float go = gate_s[r][h + 384];
      float ii = 1.f / (1.f + expf(-gi));
      float ff = 1.f / (1.f + expf(-gf));
      float gt = tanhf(gg);
      float oo = 1.f / (1.f + expf(-go));
      float memp = mem_s[r][h];
      float rst = (memp - thr > 0.f) ? thr : 0.f;
      syn = ff * syn + ii * gt;
      float mm = oo * tanhf(syn) - rst;
      mem_s[r][h] = mm;
      bool spk = (mm - thr) > 0.f;
      cnt += spk ? 1 : 0;
      unsigned long long m = __ballot(spk);
      if ((g & 63) == 0)
        spk_bits[((size_t)b * T_ + t0 + r) * 2 + ((h >> 6) & 1)] = m;
    }
    __syncthreads();
  }
  if (g < 256) atomicAdd(&count[g & 127], (unsigned int)cnt);
}

// ---------------- Kernel 3: BN params from spike counts --------------------
// Runs in BOTH paths (fast path: count==0 -> c = beta exactly).
__global__ void k_bnprep(const unsigned int* __restrict__ count,
                         const float* __restrict__ gamma,
                         const float* __restrict__ beta,
                         float* __restrict__ a, float* __restrict__ c) {
  int h = threadIdx.x;
  if (h >= H_) return;
  const float inv_n = 1.f / (float)(B_ * T_);
  float mu = (float)count[h] * inv_n;
  float var = mu * (1.f - mu);
  float ai = gamma[h] / sqrtf(var + 1e-5f);
  a[h] = ai;
  c[h] = beta[h] - mu * ai;
}

// ---------------- Kernel 4: fold BN into layer-2 weights (cg both paths) ---
__global__ void k_fold(const int* __restrict__ flag,
                       const float* __restrict__ w_ih2,
                       const float* __restrict__ b_ih2,
                       const float* __restrict__ b_hh2,
                       const float* __restrict__ a, const float* __restrict__ c,
                       float* __restrict__ W2p, float* __restrict__ cg) {
  int gi = blockIdx.x * blockDim.x + threadIdx.x;  // 0..511
  if (gi >= G_) return;
  const int fl = flag[0];
  float s = b_ih2[gi] + b_hh2[gi];
  for (int h = 0; h < H_; ++h) {
    float w = w_ih2[gi * H_ + h];
    if (!fl) W2p[h * G_ + gi] = w * a[h];  // fallback-only matrix
    s = fmaf(w, c[h], s);
  }
  cg[gi] = s;
}

// ---------------- Kernel 5: honest SLSTM layer 2 (fallback only) -----------
__global__ __launch_bounds__(512, 2) void k_slstm2(
    const int* __restrict__ flag, const unsigned long long* __restrict__ spk_bits,
    const float* __restrict__ w_hh, const float* __restrict__ W2p,
    const float* __restrict__ cg, const float* __restrict__ thr_p,
    float* __restrict__ acc_out) {
  if (flag[0]) return;  // fast path handled by k_traj
  const int g = threadIdx.x;
  const int t0 = blockIdx.x * 2;
  const float thr = thr_p[0];
  float whh[H_];
#pragma unroll
  for (int k = 0; k < H_; ++k) whh[k] = w_hh[g * H_ + k];
  const float bias = cg[g];
  __shared__ float mem_s[2][H_];
  __shared__ float gate_s[2][G_];
  float syn = 0.f, accv = 0.f;
  if (g < 256) mem_s[g >> 7][g & 127] = 0.f;
  __syncthreads();
  for (int b = 0; b < B_; ++b) {
    unsigned long long m00 = spk_bits[((size_t)b * T_ + t0) * 2 + 0];
    unsigned long long m01 = spk_bits[((size_t)b * T_ + t0) * 2 + 1];
    unsigned long long m10 = spk_bits[((size_t)b * T_ + t0 + 1) * 2 + 0];
    unsigned long long m11 = spk_bits[((size_t)b * T_ + t0 + 1) * 2 + 1];
    float s0 = bias, s1 = bias;
    while (m00) { int h = __ffsll(m00) - 1; m00 &= m00 - 1; s0 += W2p[h * G_ + g]; }
    while (m01) { int h = __ffsll(m01) - 1; m01 &= m01 - 1; s0 += W2p[(h + 64) * G_ + g]; }
    while (m10) { int h = __ffsll(m10) - 1; m10 &= m10 - 1; s1 += W2p[h * G_ + g]; }
    while (m11) { int h = __ffsll(m11) - 1; m11 &= m11 - 1; s1 += W2p[(h + 64) * G_ + g]; }
#pragma unroll
    for (int k = 0; k < H_; ++k) {
      s0 = fmaf(whh[k], mem_s[0][k], s0);
      s1 = fmaf(whh[k], mem_s[1][k], s1);
    }
    gate_s[0][g] = s0;
    gate_s[1][g] = s1;
    __syncthreads();
    if (g < 256) {
      const int r = g >> 7, h = g & 127;
      float gi = gate_s[r][h];
      float gf = gate_s[r][h + 128];
      float gg = gate_s[r][h + 256];
      float go = gate_s[r][h + 384];
      float ii = 1.f / (1.f + expf(-gi));
      float ff = 1.f / (1.f + expf(-gf));
      float gt = tanhf(gg);
      float oo = 1.f / (1.f + expf(-go));
      float memp = mem_s[r][h];
      float rst = (memp - thr > 0.f) ? thr : 0.f;
      syn = ff * syn + ii * gt;
      float mm = oo * tanhf(syn) - rst;
      mem_s[r][h] = mm;
      accv += mm;
    }
    __syncthreads();
  }
  if (g < 256) acc_out[(size_t)(t0 + (g >> 7)) * H_ + (g & 127)] = accv;
}

// ---------------- Kernel 5b: FAST layer 2 — single shared trajectory -------
// thr1>=1 -> layer-2 input = beta every row/step -> ONE 256-step trajectory.
// 1024 threads: thread i owns gate g=i>>1, half hf=i&1 -> 64 weights in 4
// NAMED f32x16 SSA values (64 VGPRs, fits the 128-cap of a 16-wave block).
#define DOT16(W, P, OFF)                                                 \
  {                                                                      \
    float4 m0_ = *(const float4*)&(P)[(OFF)];                            \
    float4 m1_ = *(const float4*)&(P)[(OFF) + 4];                        \
    float4 m2_ = *(const float4*)&(P)[(OFF) + 8];                        \
    float4 m3_ = *(const float4*)&(P)[(OFF) + 12];                       \
    a0 = fmaf(W[0], m0_.x, a0); a1 = fmaf(W[1], m0_.y, a1);              \
    a2 = fmaf(W[2], m0_.z, a2); a3 = fmaf(W[3], m0_.w, a3);              \
    a0 = fmaf(W[4], m1_.x, a0); a1 = fmaf(W[5], m1_.y, a1);              \
    a2 = fmaf(W[6], m1_.z, a2); a3 = fmaf(W[7], m1_.w, a3);              \
    a0 = fmaf(W[8], m2_.x, a0); a1 = fmaf(W[9], m2_.y, a1);              \
    a2 = fmaf(W[10], m2_.z, a2); a3 = fmaf(W[11], m2_.w, a3);            \
    a0 = fmaf(W[12], m3_.x, a0); a1 = fmaf(W[13], m3_.y, a1);            \
    a2 = fmaf(W[14], m3_.z, a2); a3 = fmaf(W[15], m3_.w, a3);            \
  }

__global__ __launch_bounds__(1024) void k_traj(
    const int* __restrict__ flag, const float* __restrict__ w_hh,
    const float* __restrict__ cg, const float* __restrict__ thr_p,
    const float* __restrict__ fc_w, const float* __restrict__ fc_b,
    float* __restrict__ out) {
  if (!flag[0]) return;
  const int i = threadIdx.x;
  const int g = i >> 1;
  const int hf = i & 1;
  const float thr = thr_p[0];

  const float* wr = w_hh + (size_t)g * H_ + hf * 64;
  f32x16 wa = *(const f32x16*)(wr);
  f32x16 wb = *(const f32x16*)(wr + 16);
  f32x16 wc = *(const f32x16*)(wr + 32);
  f32x16 wd = *(const f32x16*)(wr + 48);
  const float bias = hf ? 0.f : cg[g];

  __shared__ float mem_s[H_];
  __shared__ float gate_s[G_];
  __shared__ float red_s[H_ + 8];
  float syn = 0.f, accm = 0.f;
  if (i < H_) mem_s[i] = 0.f;
  __syncthreads();

  const float* memh = &mem_s[hf << 6];
  for (int b = 0; b < B_; ++b) {
    // phase 1: all 1024 threads, half-gate dot products
    float a0 = bias, a1 = 0.f, a2 = 0.f, a3 = 0.f;
    DOT16(wa, memh, 0) DOT16(wb, memh, 16) DOT16(wc, memh, 32) DOT16(wd, memh, 48)
    float s = (a0 + a1) + (a2 + a3);
    s += __shfl_xor(s, 1);
    if (!hf) gate_s[g] = s;
    __syncthreads();
    // phase 2: 512 threads, one transcendental each; quad-shfl gather
    if (i < 512) {
      const int h = i >> 2, r = i & 3;
      float xg = gate_s[h + (r << 7)];
      float act = (r == 2) ? tanh_fast(xg) : sigm_fast(xg);
      const int base = (i & 63) & ~3;
      float af = __shfl(act, base + 1);
      float ag = __shfl(act, base + 2);
      float ao = __shfl(act, base + 3);
      if (r == 0) {
        float memp = mem_s[h];
        float rst = (memp - thr > 0.f) ? thr : 0.f;  // honest (thr2 runtime)
        syn = af * syn + act * ag;
        float mm = ao * tanh_fast(syn) - rst;
        mem_s[h] = mm;
        accm += mm;
      }
    }
    __syncthreads();
  }
  // mean over steps -> FC (8 outputs) -> broadcast to all 512 rows
  if (i < 512 && (i & 3) == 0) red_s[i >> 2] = accm * (1.f / 256.f);
  __syncthreads();
  if (i < 8) {
    float s = fc_b[i];
    const float* fw = fc_w + i * H_;
    for (int h = 0; h < H_; ++h) s = fmaf(red_s[h], fw[h], s);
    red_s[H_ + i] = s;
  }
  __syncthreads();
  for (int idx = i; idx < T_ * 8; idx += 1024) out[idx] = red_s[H_ + (idx & 7)];
}

// ---------------- Kernel 6: final mean + FC (fallback only) ----------------
__global__ void k_out(const int* __restrict__ flag, const float* __restrict__ accv,
                      const float* __restrict__ fc_w,
                      const float* __restrict__ fc_b, float* __restrict__ out) {
  if (flag[0]) return;
  int idx = blockIdx.x * blockDim.x + threadIdx.x;  // t*8+n
  if (idx >= T_ * 8) return;
  int t = idx >> 3, n = idx & 7;
  float s = fc_b[n];
  for (int h = 0; h < H_; ++h)
    s = fmaf(accv[t * H_ + h] * (1.f / 256.f), fc_w[n * H_ + h], s);
  out[idx] = s;
}

extern "C" void kernel_launch(void* const* d_in, const int* in_sizes, int n_in,
                              void* d_out, int out_size, void* d_ws, size_t ws_size,
                              hipStream_t stream) {
  const float* x       = (const float*)d_in[0];
  const float* conv_w  = (const float*)d_in[1];
  const float* conv_b  = (const float*)d_in[2];
  const float* w_ih1   = (const float*)d_in[3];
  const float* w_hh1   = (const float*)d_in[4];
  const float* b_ih1   = (const float*)d_in[5];
  const float* b_hh1   = (const float*)d_in[6];
  const float* thr1    = (const float*)d_in[7];
  const float* w_ih2   = (const float*)d_in[8];
  const float* w_hh2   = (const float*)d_in[9];
  const float* b_ih2   = (const float*)d_in[10];
  const float* b_hh2   = (const float*)d_in[11];
  const float* thr2    = (const float*)d_in[12];
  const float* bn_g    = (const float*)d_in[13];
  const float* bn_b    = (const float*)d_in[14];
  const float* fc_w    = (const float*)d_in[15];
  const float* fc_b    = (const float*)d_in[16];
  float* out = (float*)d_out;

  char* ws = (char*)d_ws;
  unsigned int* cur1       = (unsigned int*)(ws);                    // 512 KB
  unsigned long long* spk  = (unsigned long long*)(ws + (512 << 10));// 2 MB
  unsigned int* count      = (unsigned int*)(ws + (2560 << 10));     // 512 B
  float* a                 = (float*)(ws + (2561 << 10));            // 512 B
  float* c                 = (float*)(ws + (2562 << 10));            // 512 B
  float* cg                = (float*)(ws + (2563 << 10));            // 2 KB
  float* W2p               = (float*)(ws + (2566 << 10));            // 256 KB
  float* accv              = (float*)(ws + (2822 << 10));            // 256 KB
  int* flag                = (int*)(ws + (3078 << 10));              // 4 B

  hipMemsetAsync(count, 0, H_ * sizeof(unsigned int), stream);
  k_flag<<<1, 64, 0, stream>>>(thr1, flag);
  k_conv_spike<<<(B_ * T_ + 255) / 256, 256, 0, stream>>>(flag, x, conv_w, conv_b, cur1);
  k_slstm1<<<T_ / 2, 512, 0, stream>>>(flag, cur1, w_ih1, w_hh1, b_ih1, b_hh1,
                                       thr1, spk, count);
  k_bnprep<<<1, 128, 0, stream>>>(count, bn_g, bn_b, a, c);
  k_fold<<<1, 512, 0, stream>>>(flag, w_ih2, b_ih2, b_hh2, a, c, W2p, cg);
  k_slstm2<<<T_ / 2, 512, 0, stream>>>(flag, spk, w_hh2, W2p, cg, thr2, accv);
  k_traj<<<1, 1024, 0, stream>>>(flag, w_hh2, cg, thr2, fc_w, fc_b, out);
  k_out<<<(T_ * 8 + 255) / 256, 256, 0, stream>>>(flag, accv, fc_w, fc_b, out);
}